// Round 1
// baseline (289.735 us; speedup 1.0000x reference)
//
#include <hip/hip_runtime.h>
#include <stdint.h>

#define NUM_B 128
#define NUM_P 8732
#define NUM_G 16
#define NUM_C 21
#define THR 0.5f

__device__ __forceinline__ unsigned int f2u(float f) {
    unsigned int b = __float_as_uint(f);
    return (b & 0x80000000u) ? ~b : (b | 0x80000000u);
}
__device__ __forceinline__ float u2f(unsigned int u) {
    unsigned int b = (u & 0x80000000u) ? (u & 0x7FFFFFFFu) : ~u;
    return __uint_as_float(b);
}

// ---------------------------------------------------------------- init ws
__global__ void init_kernel(unsigned long long* __restrict__ bp,
                            float* __restrict__ row_loss_l,
                            unsigned int* __restrict__ row_pos,
                            float* __restrict__ row_posc) {
    int idx = blockIdx.x * blockDim.x + threadIdx.x;
    if (idx < NUM_B * NUM_G) bp[idx] = 0ull;
    if (idx < NUM_B) {
        row_loss_l[idx] = 0.f;
        row_pos[idx]    = 0u;
        row_posc[idx]   = 0.f;
    }
}

// ---------------------------------------------------------------- matching
// per (b,i): best gt over 16 (first-index argmax), and per-gt best prior via
// packed (iou_bits<<32 | ~i) atomicMax (ties -> smallest i, like jnp.argmax).
__global__ void __launch_bounds__(256) match_kernel(
        const float* __restrict__ priors,
        const float* __restrict__ targets,
        float* __restrict__ bto, int* __restrict__ bti,
        unsigned long long* __restrict__ bp) {
    int b   = blockIdx.y;
    int tid = threadIdx.x;
    int i   = blockIdx.x * blockDim.x + tid;

    __shared__ float tg[NUM_G][4];
    __shared__ float tarea[NUM_G];
    __shared__ unsigned long long sbp[NUM_G];

    if (tid < NUM_G * 4) {
        int j = tid >> 2, d = tid & 3;
        tg[j][d] = targets[(size_t)(b * NUM_G + j) * 11 + d];
    }
    if (tid < NUM_G) sbp[tid] = 0ull;
    __syncthreads();
    if (tid < NUM_G) tarea[tid] = (tg[tid][2] - tg[tid][0]) * (tg[tid][3] - tg[tid][1]);
    __syncthreads();

    unsigned long long pk[NUM_G];
    if (i < NUM_P) {
        float pcx = priors[i * 4 + 0], pcy = priors[i * 4 + 1];
        float pw  = priors[i * 4 + 2], ph  = priors[i * 4 + 3];
        float bx1 = pcx - pw * 0.5f, by1 = pcy - ph * 0.5f;
        float bx2 = pcx + pw * 0.5f, by2 = pcy + ph * 0.5f;
        float areaB = (bx2 - bx1) * (by2 - by1);
        float best = -1.0f; int bestj = 0;
        #pragma unroll
        for (int j = 0; j < NUM_G; ++j) {
            float dx = fminf(tg[j][2], bx2) - fmaxf(tg[j][0], bx1);
            float dy = fminf(tg[j][3], by2) - fmaxf(tg[j][1], by1);
            dx = fmaxf(dx, 0.f); dy = fmaxf(dy, 0.f);
            float inter = dx * dy;
            float iou = inter / (tarea[j] + areaB - inter);
            pk[j] = ((unsigned long long)f2u(iou) << 32) |
                    (unsigned long long)(0xFFFFFFFFu - (unsigned int)i);
            if (iou > best) { best = iou; bestj = j; }  // strict > => first-index argmax
        }
        bto[(size_t)b * NUM_P + i] = best;
        bti[(size_t)b * NUM_P + i] = bestj;
    } else {
        #pragma unroll
        for (int j = 0; j < NUM_G; ++j) pk[j] = 0ull;
    }

    // wave(64) max-reduce each gt's packed value, then shared+global atomics
    #pragma unroll
    for (int j = 0; j < NUM_G; ++j) {
        unsigned long long v = pk[j];
        for (int off = 32; off > 0; off >>= 1) {
            unsigned long long o = __shfl_down(v, (unsigned)off, 64);
            v = (o > v) ? o : v;
        }
        if ((tid & 63) == 0) atomicMax(&sbp[j], v);
    }
    __syncthreads();
    if (tid < NUM_G) atomicMax(&bp[(size_t)b * NUM_G + tid], sbp[tid]);
}

// ---------------------------------------------------------------- override
// sequential j-loop per b reproduces the reference's ordered scatter (later j wins)
__global__ void override_kernel(const unsigned long long* __restrict__ bp,
                                float* __restrict__ bto, int* __restrict__ bti) {
    int b = blockIdx.x * blockDim.x + threadIdx.x;
    if (b >= NUM_B) return;
    for (int j = 0; j < NUM_G; ++j) {
        unsigned long long p = bp[(size_t)b * NUM_G + j];
        unsigned int i = 0xFFFFFFFFu - (unsigned int)(p & 0xFFFFFFFFull);
        bto[(size_t)b * NUM_P + i] = 2.0f;
        bti[(size_t)b * NUM_P + i] = j;
    }
}

// ---------------------------------------------------------------- loss pass
__global__ void __launch_bounds__(256) loss_pass_kernel(
        const float* __restrict__ loc_data,
        const float* __restrict__ conf_data,
        const float* __restrict__ priors,
        const float* __restrict__ targets,
        const float* __restrict__ bto,
        const int* __restrict__ bti,
        float* __restrict__ lc,
        float* __restrict__ row_loss_l,
        unsigned int* __restrict__ row_pos,
        float* __restrict__ row_posc) {
    int b   = blockIdx.y;
    int tid = threadIdx.x;
    int i   = blockIdx.x * blockDim.x + tid;

    float ll = 0.f, pc = 0.f; unsigned int cnt = 0u;
    if (i < NUM_P) {
        float ov = bto[(size_t)b * NUM_P + i];
        int   j  = bti[(size_t)b * NUM_P + i];
        const float* tg = targets + (size_t)(b * NUM_G + j) * 11;
        bool pos = ov >= THR;
        int label = (int)tg[10];
        int conf_t = pos ? (label + 1) : 0;

        const float* cd = conf_data + (size_t)(b * NUM_P + i) * NUM_C;
        float cv[NUM_C];
        #pragma unroll
        for (int c = 0; c < NUM_C; ++c) cv[c] = cd[c];
        float mx = cv[0];
        #pragma unroll
        for (int c = 1; c < NUM_C; ++c) mx = fmaxf(mx, cv[c]);
        float s = 0.f;
        #pragma unroll
        for (int c = 0; c < NUM_C; ++c) s += expf(cv[c] - mx);
        float lse = logf(s) + mx;
        float lca = lse - cv[conf_t];
        lc[(size_t)b * NUM_P + i] = pos ? 0.f : lca;

        if (pos) {
            cnt = 1u; pc = lca;
            float pcx = priors[i * 4 + 0], pcy = priors[i * 4 + 1];
            float pw  = priors[i * 4 + 2], ph  = priors[i * 4 + 3];
            float m0 = tg[0], m1 = tg[1], m2 = tg[2], m3 = tg[3];
            float t[10];
            t[0] = ((m0 + m2) * 0.5f - pcx) / (0.1f * pw);
            t[1] = ((m1 + m3) * 0.5f - pcy) / (0.1f * ph);
            t[2] = logf((m2 - m0) / pw) / 0.2f;
            t[3] = logf((m3 - m1) / ph) / 0.2f;
            t[4] = logf(tg[4] / pw + 0.1f) / 0.2f;
            t[5] = logf(tg[5] / ph + 0.1f) / 0.2f;
            t[6] = logf(tg[6] / pw + 0.1f) / 0.2f;
            t[7] = logf(tg[7] / ph + 0.1f) / 0.2f;
            t[8] = (tg[8] - pcx) / (0.1f * pw);
            t[9] = (tg[9] - pcy) / (0.1f * ph);
            const float* ld = loc_data + (size_t)(b * NUM_P + i) * 10;
            #pragma unroll
            for (int d = 0; d < 10; ++d) {
                float df = ld[d] - t[d];
                float ad = fabsf(df);
                ll += (ad < 1.f) ? 0.5f * df * df : (ad - 0.5f);
            }
        }
    }

    // block reduce (4 waves)
    for (int off = 32; off > 0; off >>= 1) {
        ll  += __shfl_down(ll, (unsigned)off, 64);
        pc  += __shfl_down(pc, (unsigned)off, 64);
        cnt += __shfl_down(cnt, (unsigned)off, 64);
    }
    __shared__ float wll[4], wpc[4];
    __shared__ unsigned int wcnt[4];
    int wave = tid >> 6;
    if ((tid & 63) == 0) { wll[wave] = ll; wpc[wave] = pc; wcnt[wave] = cnt; }
    __syncthreads();
    if (tid == 0) {
        float a = 0.f, c = 0.f; unsigned int n = 0u;
        #pragma unroll
        for (int w = 0; w < 4; ++w) { a += wll[w]; c += wpc[w]; n += wcnt[w]; }
        atomicAdd(&row_loss_l[b], a);
        atomicAdd(&row_posc[b], c);
        atomicAdd(&row_pos[b], n);
    }
}

// ---------------------------------------------------------------- per-row top-k via radix select
__global__ void __launch_bounds__(256) select_kernel(
        const float* __restrict__ lc,
        const unsigned int* __restrict__ row_pos,
        const float* __restrict__ row_posc,
        float* __restrict__ row_loss_c) {
    int b   = blockIdx.x;
    int tid = threadIdx.x;
    __shared__ float slc[NUM_P];
    __shared__ unsigned int hist[256];
    __shared__ unsigned int s_prefix;
    __shared__ int s_kk;

    for (int idx = tid; idx < NUM_P; idx += 256)
        slc[idx] = lc[(size_t)b * NUM_P + idx];

    int npos = (int)row_pos[b];
    int k = 3 * npos; if (k > NUM_P - 1) k = NUM_P - 1;
    if (k == 0) { if (tid == 0) row_loss_c[b] = row_posc[b]; return; }
    if (tid == 0) { s_prefix = 0u; s_kk = k; }
    __syncthreads();

    for (int pass = 0; pass < 4; ++pass) {
        int shift = 24 - 8 * pass;
        hist[tid] = 0u;
        __syncthreads();
        unsigned int prefix = s_prefix;
        unsigned int hmask  = (pass == 0) ? 0u : (0xFFFFFFFFu << (shift + 8));
        for (int idx = tid; idx < NUM_P; idx += 256) {
            unsigned int u = f2u(slc[idx]);
            if ((u & hmask) == prefix) atomicAdd(&hist[(u >> shift) & 255u], 1u);
        }
        __syncthreads();
        if (tid == 0) {
            int kk = s_kk; unsigned int acc = 0u;
            for (int bin = 255; bin >= 0; --bin) {
                unsigned int h = hist[bin];
                if (acc + h >= (unsigned int)kk) {
                    s_kk = kk - (int)acc;
                    s_prefix = prefix | ((unsigned int)bin << shift);
                    break;
                }
                acc += h;
            }
        }
        __syncthreads();
    }

    unsigned int Tu = s_prefix;
    int m = s_kk;                       // how many ties at value Tu to take
    float local = 0.f;
    for (int idx = tid; idx < NUM_P; idx += 256) {
        float v = slc[idx];
        if (f2u(v) > Tu) local += v;
    }
    for (int off = 32; off > 0; off >>= 1) local += __shfl_down(local, (unsigned)off, 64);
    __shared__ float wsum[4];
    if ((tid & 63) == 0) wsum[tid >> 6] = local;
    __syncthreads();
    if (tid == 0) {
        float s = wsum[0] + wsum[1] + wsum[2] + wsum[3];
        row_loss_c[b] = row_posc[b] + s + (float)m * u2f(Tu);
    }
}

// ---------------------------------------------------------------- finalize
__global__ void finalize_kernel(const float* __restrict__ row_loss_l,
                                const float* __restrict__ row_loss_c,
                                const unsigned int* __restrict__ row_pos,
                                float* __restrict__ out) {
    __shared__ float sl[128], sc[128];
    __shared__ unsigned int sn[128];
    int t = threadIdx.x;
    sl[t] = row_loss_l[t]; sc[t] = row_loss_c[t]; sn[t] = row_pos[t];
    __syncthreads();
    for (int off = 64; off > 0; off >>= 1) {
        if (t < off) { sl[t] += sl[t + off]; sc[t] += sc[t + off]; sn[t] += sn[t + off]; }
        __syncthreads();
    }
    if (t == 0) {
        float N = (float)sn[0];
        out[0] = sl[0] / N;
        out[1] = sc[0] / N;
    }
}

extern "C" void kernel_launch(void* const* d_in, const int* in_sizes, int n_in,
                              void* d_out, int out_size, void* d_ws, size_t ws_size,
                              hipStream_t stream) {
    const float* loc_data  = (const float*)d_in[0];
    const float* conf_data = (const float*)d_in[1];
    const float* priors    = (const float*)d_in[2];
    const float* targets   = (const float*)d_in[3];
    float* out = (float*)d_out;

    char* ws = (char*)d_ws;
    size_t off = 0;
    float* lc  = (float*)(ws + off); off += (size_t)NUM_B * NUM_P * sizeof(float);
    float* bto = (float*)(ws + off); off += (size_t)NUM_B * NUM_P * sizeof(float);
    int*   bti = (int*)(ws + off);   off += (size_t)NUM_B * NUM_P * sizeof(int);
    unsigned long long* bp = (unsigned long long*)(ws + off);
    off += (size_t)NUM_B * NUM_G * sizeof(unsigned long long);
    float* row_loss_l = (float*)(ws + off); off += NUM_B * sizeof(float);
    unsigned int* row_pos = (unsigned int*)(ws + off); off += NUM_B * sizeof(unsigned int);
    float* row_posc   = (float*)(ws + off); off += NUM_B * sizeof(float);
    float* row_loss_c = (float*)(ws + off); off += NUM_B * sizeof(float);

    const int PB = (NUM_P + 255) / 256;  // 35

    init_kernel<<<8, 256, 0, stream>>>(bp, row_loss_l, row_pos, row_posc);
    match_kernel<<<dim3(PB, NUM_B), 256, 0, stream>>>(priors, targets, bto, bti, bp);
    override_kernel<<<1, 128, 0, stream>>>(bp, bto, bti);
    loss_pass_kernel<<<dim3(PB, NUM_B), 256, 0, stream>>>(
        loc_data, conf_data, priors, targets, bto, bti,
        lc, row_loss_l, row_pos, row_posc);
    select_kernel<<<NUM_B, 256, 0, stream>>>(lc, row_pos, row_posc, row_loss_c);
    finalize_kernel<<<1, 128, 0, stream>>>(row_loss_l, row_loss_c, row_pos, out);
}